// Round 7
// baseline (963.925 us; speedup 1.0000x reference)
//
#include <hip/hip_runtime.h>
#include <cstdint>
#include <cstddef>

// Problem constants (hardcoded per reference setup_inputs)
#define B_    4
#define Q_    8192
#define E_    256
#define H_    8
#define L_    4
#define P_    4
#define HD_   32
#define VLEN_ 21760   // 128^2 + 64^2 + 32^2 + 16^2
#define K_    256

// ---------------- Kernel 1: value projection for ONE batch (all fp32) ----------------
// C[pix][n] = sum_k value_b[pix][k] * V_W[n][k]; C row-major (21760, 256) fp32.
__global__ __launch_bounds__(256)
void gemm_vproj(const float* __restrict__ A,      // value + b*VLEN*256
                const float* __restrict__ W,      // V_W (256,256)
                float* __restrict__ C)            // v_ws (21760,256) fp32
{
  __shared__ float As[64][17];
  __shared__ float Ws[64][17];

  const int t  = threadIdx.x;
  const int tx = t & 15, ty = t >> 4;
  const int bm = blockIdx.x, bn = blockIdx.y;
  const int lr = t >> 2;
  const int lc = (t & 3) * 4;

  float acc[4][4] = {};

  for (int k0 = 0; k0 < K_; k0 += 16) {
    {
      const float4 v = *(const float4*)(A + (size_t)(bm * 64 + lr) * K_ + k0 + lc);
      As[lr][lc + 0] = v.x; As[lr][lc + 1] = v.y; As[lr][lc + 2] = v.z; As[lr][lc + 3] = v.w;
    }
    {
      const float4 v = *(const float4*)(W + (size_t)(bn * 64 + lr) * K_ + k0 + lc);
      Ws[lr][lc + 0] = v.x; Ws[lr][lc + 1] = v.y; Ws[lr][lc + 2] = v.z; Ws[lr][lc + 3] = v.w;
    }
    __syncthreads();
#pragma unroll
    for (int kk = 0; kk < 16; ++kk) {
      float a0 = As[ty * 4 + 0][kk], a1 = As[ty * 4 + 1][kk];
      float a2 = As[ty * 4 + 2][kk], a3 = As[ty * 4 + 3][kk];
      float w0 = Ws[tx * 4 + 0][kk], w1 = Ws[tx * 4 + 1][kk];
      float w2 = Ws[tx * 4 + 2][kk], w3 = Ws[tx * 4 + 3][kk];
      acc[0][0] += a0 * w0; acc[0][1] += a0 * w1; acc[0][2] += a0 * w2; acc[0][3] += a0 * w3;
      acc[1][0] += a1 * w0; acc[1][1] += a1 * w1; acc[1][2] += a1 * w2; acc[1][3] += a1 * w3;
      acc[2][0] += a2 * w0; acc[2][1] += a2 * w1; acc[2][2] += a2 * w2; acc[2][3] += a2 * w3;
      acc[3][0] += a3 * w0; acc[3][1] += a3 * w1; acc[3][2] += a3 * w2; acc[3][3] += a3 * w3;
    }
    __syncthreads();
  }

#pragma unroll
  for (int i = 0; i < 4; ++i)
#pragma unroll
    for (int j = 0; j < 4; ++j) {
      const int gm = bm * 64 + ty * 4 + i;
      const int gn = bn * 64 + tx * 4 + j;
      C[(size_t)gm * 256 + gn] = acc[i][j];
    }
}

// ---------------- Kernel 2: fused offsets/attn GEMM + softmax + sampling (ONE batch) ----------------
// One block = 16 consecutive queries. Exact fp32 projection, tanh/softmax,
// float bilinear taps, gather from fp32 v_ws, write fp32 pre-projection rows
// into outpre (= d_out + b*Q*256).
__global__ __launch_bounds__(256)
void fused_offattn_sample(const float* __restrict__ queries,     // + b*Q*256
                          const float* __restrict__ ref_points,  // + b*Q*8
                          const float* __restrict__ off_W,
                          const float* __restrict__ off_b,
                          const float* __restrict__ attn_W,
                          const float* __restrict__ attn_b,
                          const float* __restrict__ v_ws,        // (21760,256) fp32
                          float* __restrict__ outpre)            // (8192,256) fp32
{
  __shared__ float qs[16][260];            // query tile fp32 (pad 4)
  __shared__ float wc[64][17];             // weight k-chunk
  __shared__ float s_px[16][128];          // x pixel coord per (q, h*16+l*4+p)
  __shared__ float s_py[16][128];          // y pixel coord
  __shared__ float s_a[16][128];           // softmaxed attention weights
  __shared__ float refs[16][8];            // ref_points per query (l, xy)
  __shared__ int   s_idx[128 * 4];
  __shared__ float s_w[128 * 4];

  const int t     = threadIdx.x;
  const int lane  = t & 63;                // column within 64-col group
  const int wv    = t >> 6;                // wave id: q rows {wv, wv+4, wv+8, wv+12}
  const int qbase = blockIdx.x * 16;       // local query base within this batch

  // ---- load query tile + ref points
  {
    const int r  = t >> 4;
    const int c0 = (t & 15) * 16;
    const float4* src = (const float4*)(queries + (size_t)(qbase + r) * K_ + c0);
    *(float4*)&qs[r][c0 + 0]  = src[0];
    *(float4*)&qs[r][c0 + 4]  = src[1];
    *(float4*)&qs[r][c0 + 8]  = src[2];
    *(float4*)&qs[r][c0 + 12] = src[3];
  }
  if (t < 128) refs[t >> 3][t & 7] = ref_points[(size_t)(qbase + (t >> 3)) * 8 + (t & 7)];

  // ---- offset columns (0..255): 4 groups of 64; col e = h*32 + l*8 + p*2 + xy
  for (int cg = 0; cg < 4; ++cg) {
    const int col = cg * 64 + lane;
    float a0 = 0.f, a1 = 0.f, a2 = 0.f, a3 = 0.f;
    for (int k0 = 0; k0 < K_; k0 += 16) {
      __syncthreads();
      {
        const float4 v = *(const float4*)(off_W + (size_t)(cg * 64 + (t >> 2)) * K_ + k0 + (t & 3) * 4);
        wc[t >> 2][(t & 3) * 4 + 0] = v.x; wc[t >> 2][(t & 3) * 4 + 1] = v.y;
        wc[t >> 2][(t & 3) * 4 + 2] = v.z; wc[t >> 2][(t & 3) * 4 + 3] = v.w;
      }
      __syncthreads();
#pragma unroll
      for (int kk = 0; kk < 16; ++kk) {
        const float w = wc[lane][kk];
        a0 += w * qs[wv +  0][k0 + kk];
        a1 += w * qs[wv +  4][k0 + kk];
        a2 += w * qs[wv +  8][k0 + kk];
        a3 += w * qs[wv + 12][k0 + kk];
      }
    }
    const float bias = off_b[col];
    const int l  = (col >> 3) & 3;
    const int Wl = 128 >> l;
    const float sc = 0.5f * (float)(Wl - 1);
    const int xy = col & 1;
    float accs[4] = {a0, a1, a2, a3};
#pragma unroll
    for (int i = 0; i < 4; ++i) {
      const int q = wv + 4 * i;
      float loc = refs[q][l * 2 + xy] + tanhf(accs[i] + bias);   // OFFSET_SCALE=1
      loc = fminf(fmaxf(loc, -1.f), 1.f);
      const float pix = (loc + 1.f) * sc;                        // [0, Wl-1]
      const float other = __shfl_xor(pix, 1);                    // partner coordinate
      if ((lane & 1) == 0) {                                     // xy==0 lane holds x
        s_px[q][col >> 1] = pix;                                 // col>>1 = h*16+l*4+p
        s_py[q][col >> 1] = other;
      }
    }
  }

  // ---- attention columns: 2 groups of 64 (logit index li = h*16 + l*4 + p)
  for (int cg = 0; cg < 2; ++cg) {
    const int li = cg * 64 + lane;
    float a0 = 0.f, a1 = 0.f, a2 = 0.f, a3 = 0.f;
    for (int k0 = 0; k0 < K_; k0 += 16) {
      __syncthreads();
      {
        const float4 v = *(const float4*)(attn_W + (size_t)(cg * 64 + (t >> 2)) * K_ + k0 + (t & 3) * 4);
        wc[t >> 2][(t & 3) * 4 + 0] = v.x; wc[t >> 2][(t & 3) * 4 + 1] = v.y;
        wc[t >> 2][(t & 3) * 4 + 2] = v.z; wc[t >> 2][(t & 3) * 4 + 3] = v.w;
      }
      __syncthreads();
#pragma unroll
      for (int kk = 0; kk < 16; ++kk) {
        const float w = wc[lane][kk];
        a0 += w * qs[wv +  0][k0 + kk];
        a1 += w * qs[wv +  4][k0 + kk];
        a2 += w * qs[wv +  8][k0 + kk];
        a3 += w * qs[wv + 12][k0 + kk];
      }
    }
    const float bias = attn_b[li];
    float accs[4] = {a0, a1, a2, a3};
#pragma unroll
    for (int i = 0; i < 4; ++i) {
      const int q = wv + 4 * i;
      const float logit = accs[i] + bias;
      // softmax over the 16-lane group (one head, fixed q)
      float mx = logit;
#pragma unroll
      for (int msk = 1; msk < 16; msk <<= 1) mx = fmaxf(mx, __shfl_xor(mx, msk));
      const float e = __expf(logit - mx);
      float s = e;
#pragma unroll
      for (int msk = 1; msk < 16; msk <<= 1) s += __shfl_xor(s, msk);
      s_a[q][li] = e / s;
    }
  }

  // ---- sampling: loop over the 16 queries
  for (int q = 0; q < 16; ++q) {
    __syncthreads();
    if (t < 128) {                          // t = h*16 + l*4 + p
      const float a = s_a[q][t];
      const int l  = (t >> 2) & 3;
      const int Wl = 128 >> l;
      const int base = (l == 0) ? 0 : (l == 1) ? 16384 : (l == 2) ? 20480 : 21504;
      const float x = s_px[q][t], y = s_py[q][t];
      const float x0f = floorf(x), y0f = floorf(y);
      const float wx = x - x0f, wy = y - y0f;
      const int x0 = min(max((int)x0f, 0), Wl - 1);
      const int x1 = min(x0 + 1, Wl - 1);
      const int y0 = min(max((int)y0f, 0), Wl - 1);
      const int y1 = min(y0 + 1, Wl - 1);
      s_idx[t * 4 + 0] = base + y0 * Wl + x0;
      s_idx[t * 4 + 1] = base + y0 * Wl + x1;
      s_idx[t * 4 + 2] = base + y1 * Wl + x0;
      s_idx[t * 4 + 3] = base + y1 * Wl + x1;
      s_w[t * 4 + 0] = a * (1.f - wy) * (1.f - wx);
      s_w[t * 4 + 1] = a * (1.f - wy) * wx;
      s_w[t * 4 + 2] = a * wy * (1.f - wx);
      s_w[t * 4 + 3] = a * wy * wx;
    }
    __syncthreads();
    // gather: thread = (h, c); v layout: pix*256 + h*32 + c
    const int h = t >> 5, c = t & 31;
    const float* vb = v_ws + h * 32 + c;
    float acc = 0.f;
#pragma unroll
    for (int j = 0; j < 16; ++j) {
      const int g = h * 16 + j;
      acc += s_w[g * 4 + 0] * vb[(size_t)s_idx[g * 4 + 0] * 256]
           + s_w[g * 4 + 1] * vb[(size_t)s_idx[g * 4 + 1] * 256]
           + s_w[g * 4 + 2] * vb[(size_t)s_idx[g * 4 + 2] * 256]
           + s_w[g * 4 + 3] * vb[(size_t)s_idx[g * 4 + 3] * 256];
    }
    outpre[(size_t)(qbase + q) * 256 + t] = acc;   // fp32
  }
}

// ---------------- Kernel 3: in-place output projection (fp32, race-free) ----------------
// One block owns 64 rows of D fully: caches 64x256 fp32 in LDS, then computes
// all 4 column tiles of D = pre @ out_W^T and stores. No cross-block sharing.
__global__ __launch_bounds__(256)
void gemm_out_inplace(float* __restrict__ D,       // d_out (32768,256) fp32
                      const float* __restrict__ Wout)
{
  __shared__ float As[64][256];   // 64 KB: this block's pre rows
  __shared__ float Ws[64][17];

  const int t  = threadIdx.x;
  const int tx = t & 15, ty = t >> 4;
  const int bm = blockIdx.x;

  // cache this block's 64 rows (16384 floats = 4096 float4)
#pragma unroll
  for (int i = 0; i < 16; ++i) {
    const int e = t + i * 256;               // float4 index 0..4095
    const int r = e >> 6, cc = e & 63;
    *(float4*)&As[r][cc * 4] = *(const float4*)(D + (size_t)(bm * 64 + r) * 256 + cc * 4);
  }

  for (int bn = 0; bn < 4; ++bn) {
    float acc[4][4] = {};
    for (int k0 = 0; k0 < K_; k0 += 16) {
      __syncthreads();   // protect Ws (and As on first iter) before rewrite
      {
        const float4 v = *(const float4*)(Wout + (size_t)(bn * 64 + (t >> 2)) * K_ + k0 + (t & 3) * 4);
        Ws[t >> 2][(t & 3) * 4 + 0] = v.x; Ws[t >> 2][(t & 3) * 4 + 1] = v.y;
        Ws[t >> 2][(t & 3) * 4 + 2] = v.z; Ws[t >> 2][(t & 3) * 4 + 3] = v.w;
      }
      __syncthreads();
#pragma unroll
      for (int kk = 0; kk < 16; ++kk) {
        const float a0 = As[ty * 4 + 0][k0 + kk];
        const float a1 = As[ty * 4 + 1][k0 + kk];
        const float a2 = As[ty * 4 + 2][k0 + kk];
        const float a3 = As[ty * 4 + 3][k0 + kk];
        const float w0 = Ws[tx * 4 + 0][kk], w1 = Ws[tx * 4 + 1][kk];
        const float w2 = Ws[tx * 4 + 2][kk], w3 = Ws[tx * 4 + 3][kk];
        acc[0][0] += a0 * w0; acc[0][1] += a0 * w1; acc[0][2] += a0 * w2; acc[0][3] += a0 * w3;
        acc[1][0] += a1 * w0; acc[1][1] += a1 * w1; acc[1][2] += a1 * w2; acc[1][3] += a1 * w3;
        acc[2][0] += a2 * w0; acc[2][1] += a2 * w1; acc[2][2] += a2 * w2; acc[2][3] += a2 * w3;
        acc[3][0] += a3 * w0; acc[3][1] += a3 * w1; acc[3][2] += a3 * w2; acc[3][3] += a3 * w3;
      }
    }
#pragma unroll
    for (int i = 0; i < 4; ++i)
#pragma unroll
      for (int j = 0; j < 4; ++j) {
        const int gm = bm * 64 + ty * 4 + i;
        const int gn = bn * 64 + tx * 4 + j;
        D[(size_t)gm * 256 + gn] = acc[i][j];    // own rows; As is a private copy
      }
  }
}

extern "C" void kernel_launch(void* const* d_in, const int* in_sizes, int n_in,
                              void* d_out, int out_size, void* d_ws, size_t ws_size,
                              hipStream_t stream)
{
  (void)in_sizes; (void)n_in; (void)out_size; (void)ws_size;
  const float* queries    = (const float*)d_in[0];
  const float* ref_points = (const float*)d_in[1];
  const float* value      = (const float*)d_in[2];
  // d_in[3] = value_spatial_shapes (int32) — compile-time constants here
  const float* V_W    = (const float*)d_in[4];
  const float* off_W  = (const float*)d_in[5];
  const float* off_b  = (const float*)d_in[6];
  const float* attn_W = (const float*)d_in[7];
  const float* attn_b = (const float*)d_in[8];
  const float* out_W  = (const float*)d_in[9];

  // Workspace: one batch of projected values, (21760 x 256) fp32 = 22,282,240 B.
  float* v_ws = (float*)d_ws;

  // Per-batch: vproj(b) -> sample(b); stream order serializes the v_ws reuse.
  for (int b = 0; b < B_; ++b) {
    gemm_vproj<<<dim3(VLEN_ / 64, 4), 256, 0, stream>>>(
        value + (size_t)b * VLEN_ * K_, V_W, v_ws);
    fused_offattn_sample<<<Q_ / 16, 256, 0, stream>>>(
        queries + (size_t)b * Q_ * K_, ref_points + (size_t)b * Q_ * 8,
        off_W, off_b, attn_W, attn_b, v_ws,
        (float*)d_out + (size_t)b * Q_ * 256);
  }
  // Output projection, in place on d_out (race-free).
  gemm_out_inplace<<<(B_ * Q_) / 64, 256, 0, stream>>>((float*)d_out, out_W);
}